// Round 1
// baseline (349.541 us; speedup 1.0000x reference)
//
#include <hip/hip_runtime.h>
#include <hip/hip_bf16.h>
#include <math.h>

// Problem shape (fixed by reference): z [4,64,16,32,32] fp32, embedding [1024,64] fp32
// N = 65536 tokens, C = 64, K = 1024, DHW = 16384 (channel stride in z / out)
#define CH     64
#define DHWC   16384
#define NTOK   65536
#define KCODES 1024
#define OUT_ELEMS 4194304   // 4*64*16*32*32

struct Ws {
  double sum_z2;      // sum over all z^2
  double sum_e2;      // sum over all e^2 (= sum_k ||e_k||^2)
  double loss_sum;    // sum over all elements of (z_q - z)^2
  double pad;
  double sum_z[CH];   // per-channel sum of z over all tokens
  double sum_e[CH];   // per-channel sum of e over all codes
  float  e_norm[KCODES];
  int    counts[KCODES];
};

// ---- prep: per-code squared norms + sum_e2 -------------------------------
__global__ void vq_prep_enorm(const float* __restrict__ emb, Ws* __restrict__ ws) {
  const int k = blockIdx.x * 64 + threadIdx.x;   // grid 16 x 64
  const float4* row = (const float4*)(emb + (size_t)k * CH);
  float s2 = 0.f;
  #pragma unroll
  for (int i = 0; i < 16; ++i) {
    float4 v = row[i];
    s2 = fmaf(v.x, v.x, s2);
    s2 = fmaf(v.y, v.y, s2);
    s2 = fmaf(v.z, v.z, s2);
    s2 = fmaf(v.w, v.w, s2);
  }
  ws->e_norm[k] = s2;
  // wave-reduce s2 -> one double atomic per block (block = 1 wave)
  float r = s2;
  #pragma unroll
  for (int off = 32; off > 0; off >>= 1) r += __shfl_down(r, off);
  if (threadIdx.x == 0) atomicAdd(&ws->sum_e2, (double)r);
}

// ---- prep: per-channel sums of embedding ---------------------------------
__global__ void vq_prep_esum(const float* __restrict__ emb, Ws* __restrict__ ws) {
  // 1 block x 256 threads: thread (c = tid&63, q = tid>>6) sums codes k ≡ q (mod 4)
  const int tid = threadIdx.x;
  const int c = tid & 63, q = tid >> 6;
  float s = 0.f;
  for (int k = q; k < KCODES; k += 4) s += emb[(size_t)k * CH + c];
  __shared__ float sh[256];
  sh[tid] = s;
  __syncthreads();
  if (tid < 64) {
    float t = sh[tid] + sh[tid + 64] + sh[tid + 128] + sh[tid + 192];
    ws->sum_e[tid] = (double)t;
  }
}

// ---- prep: per-channel sums of z + sum of z^2 ----------------------------
__global__ void vq_zsum(const float* __restrict__ z, Ws* __restrict__ ws) {
  // grid 256 blocks x 256 threads; block p handles plane (b = p>>6, c = p&63)
  const int p = blockIdx.x;
  const int tid = threadIdx.x;
  const float* base = z + (size_t)p * DHWC;
  float s = 0.f, s2 = 0.f;
  #pragma unroll 4
  for (int i = tid; i < DHWC; i += 256) {
    float v = base[i];
    s += v;
    s2 = fmaf(v, v, s2);
  }
  __shared__ float sh[512];
  sh[tid] = s; sh[256 + tid] = s2;
  __syncthreads();
  for (int off = 128; off > 0; off >>= 1) {
    if (tid < off) { sh[tid] += sh[tid + off]; sh[256 + tid] += sh[256 + tid + off]; }
    __syncthreads();
  }
  if (tid == 0) {
    atomicAdd(&ws->sum_z[p & 63], (double)sh[0]);
    atomicAdd(&ws->sum_z2, (double)sh[256]);
  }
}

// ---- main: distances + argmin + gather + straight-through output ---------
__global__ __launch_bounds__(256, 4)
void vq_main(const float* __restrict__ z, const float* __restrict__ emb,
             float* __restrict__ out, Ws* __restrict__ ws) {
  const int tid  = threadIdx.x;
  const int lane = tid & 63;        // token within block
  const int w    = tid >> 6;        // wave id: handles codes [w*256, w*256+256)
  const int n    = blockIdx.x * 64 + lane;
  const int b    = n >> 14;         // n / 16384
  const int s    = n & 16383;
  const float* zb = z + (size_t)b * (CH * DHWC) + s;   // channel c at zb[c*DHWC]

  // token vector -> 64 VGPRs (coalesced: lanes differ in s)
  float zr[CH];
  #pragma unroll
  for (int c = 0; c < CH; ++c) zr[c] = zb[(size_t)c * DHWC];
  float znorm = 0.f;
  #pragma unroll
  for (int c = 0; c < CH; ++c) znorm = fmaf(zr[c], zr[c], znorm);

  // wave-uniform code range; readfirstlane to let the compiler prove uniformity
  const int k0 = __builtin_amdgcn_readfirstlane(w * 256);
  const float* __restrict__ en = ws->e_norm;

  float best = 3.4e38f;
  int bestk = 0;
  for (int k = k0; k < k0 + 256; ++k) {
    const float* __restrict__ ek = emb + (size_t)k * CH;
    float dot = 0.f;
    #pragma unroll
    for (int c = 0; c < CH; ++c) dot = fmaf(zr[c], ek[c], dot);
    // match reference rounding: t = fl(znorm + enorm); d = fl(t - 2*dot)
    float t = znorm + en[k];
    float d = fmaf(-2.f, dot, t);
    if (d < best) { best = d; bestk = k; }   // strict < keeps lowest k on ties
  }

  // combine the 4 per-wave results per token
  __shared__ float sd[256];
  __shared__ int   sk[256];
  sd[tid] = best; sk[tid] = bestk;
  __syncthreads();
  float fb = sd[lane];
  int   fk = sk[lane];
  #pragma unroll
  for (int j = 1; j < 4; ++j) {             // j ascending == k ascending
    float dj = sd[j * 64 + lane];
    int   kj = sk[j * 64 + lane];
    if (dj < fb) { fb = dj; fk = kj; }
  }
  if (w == 0) atomicAdd(&ws->counts[fk], 1);

  // epilogue: thread handles channels [w*16, w*16+16) of its token
  const float* __restrict__ eq = emb + (size_t)fk * CH;
  float lpart = 0.f;
  #pragma unroll
  for (int c2 = 0; c2 < 16; ++c2) {
    const int c = w * 16 + c2;
    float zc = zb[(size_t)c * DHWC];        // L1-hot reload (avoids dynamic VGPR indexing)
    float q  = eq[c];
    float dd = q - zc;                      // fl(z_q - z)
    out[(size_t)(b * CH + c) * DHWC + s] = zc + dd;   // straight-through, ref rounding
    lpart = fmaf(dd, dd, lpart);
  }

  __syncthreads();                          // sd free for reuse
  sd[tid] = lpart;
  __syncthreads();
  for (int off = 128; off > 0; off >>= 1) {
    if (tid < off) sd[tid] += sd[tid + off];
    __syncthreads();
  }
  if (tid == 0) atomicAdd(&ws->loss_sum, (double)sd[0]);
}

// ---- final: scalars ------------------------------------------------------
__global__ void vq_final(Ws* __restrict__ ws, float* __restrict__ out_scalars) {
  const int tid = threadIdx.x;              // 1 block x 1024 threads
  float p = (float)ws->counts[tid] * (1.0f / 65536.0f);
  float term = p * logf(p + 1e-10f);
  __shared__ float sh[1024];
  sh[tid] = term;
  __syncthreads();
  for (int off = 512; off > 0; off >>= 1) {
    if (tid < off) sh[tid] += sh[tid + off];
    __syncthreads();
  }
  if (tid == 0) {
    float perp = expf(-sh[0]);
    double m = ws->loss_sum / (double)OUT_ELEMS;
    float mf = (float)m;
    float loss = mf + 0.25f * mf;
    double sdot = 0.0;
    #pragma unroll
    for (int c = 0; c < CH; ++c) sdot += ws->sum_z[c] * ws->sum_e[c];
    double md = ws->sum_z2 / (double)NTOK + ws->sum_e2 / (double)KCODES
              - 2.0 * sdot / ((double)NTOK * (double)KCODES);
    out_scalars[0] = loss;
    out_scalars[1] = perp;
    out_scalars[2] = (float)md;
  }
}

extern "C" void kernel_launch(void* const* d_in, const int* in_sizes, int n_in,
                              void* d_out, int out_size, void* d_ws, size_t ws_size,
                              hipStream_t stream) {
  const float* z   = (const float*)d_in[0];
  const float* emb = (const float*)d_in[1];
  float* out = (float*)d_out;
  Ws* ws = (Ws*)d_ws;

  hipMemsetAsync(d_ws, 0, sizeof(Ws), stream);
  vq_prep_enorm<<<16, 64, 0, stream>>>(emb, ws);
  vq_prep_esum <<<1, 256, 0, stream>>>(emb, ws);
  vq_zsum      <<<256, 256, 0, stream>>>(z, ws);
  vq_main      <<<1024, 256, 0, stream>>>(z, emb, out, ws);
  vq_final     <<<1, 1024, 0, stream>>>(ws, out + OUT_ELEMS);
}

// Round 2
// 290.254 us; speedup vs baseline: 1.2043x; 1.2043x over previous
//
#include <hip/hip_runtime.h>
#include <hip/hip_bf16.h>
#include <math.h>

// Problem shape (fixed by reference): z [4,64,16,32,32] fp32, embedding [1024,64] fp32
// N = 65536 tokens, C = 64, K = 1024, DHW = 16384 (channel stride in z / out)
#define CH     64
#define DHWC   16384
#define NTOK   65536
#define KCODES 1024
#define OUT_ELEMS 4194304   // 4*64*16*32*32

struct Ws {
  double sum_z2;      // sum over all z^2
  double sum_e2;      // sum over all e^2 (= sum_k ||e_k||^2)
  double loss_sum;    // sum over all elements of (z_q - z)^2
  double pad;
  double sum_z[CH];   // per-channel sum of z over all tokens
  double sum_e[CH];   // per-channel sum of e over all codes
  float  e_norm[KCODES];
  int    counts[KCODES];
};

// ---- prep: per-code norms + per-channel sums + sum_e2, one pass ----------
// grid 16 x 256; block j handles codes [j*64, j*64+64)
__global__ void vq_eprep(const float* __restrict__ emb, Ws* __restrict__ ws) {
  __shared__ float tile[64][68];          // row stride 68 floats (272 B, 16B-aligned)
  __shared__ float red[256];
  const int tid = threadIdx.x;
  const int r = tid >> 2;                 // code row within block tile
  const int q = tid & 3;                  // quarter of the 64-channel row
  const int k = blockIdx.x * 64 + r;
  const float4* src = (const float4*)(emb + (size_t)k * CH + q * 16);
  float4 a = src[0], b = src[1], c = src[2], d = src[3];
  float4* dst = (float4*)(&tile[r][q * 16]);
  dst[0] = a; dst[1] = b; dst[2] = c; dst[3] = d;
  // partial squared norm of this thread's 16 values
  float s2 = 0.f;
  s2 = fmaf(a.x,a.x,s2); s2 = fmaf(a.y,a.y,s2); s2 = fmaf(a.z,a.z,s2); s2 = fmaf(a.w,a.w,s2);
  s2 = fmaf(b.x,b.x,s2); s2 = fmaf(b.y,b.y,s2); s2 = fmaf(b.z,b.z,s2); s2 = fmaf(b.w,b.w,s2);
  s2 = fmaf(c.x,c.x,s2); s2 = fmaf(c.y,c.y,s2); s2 = fmaf(c.z,c.z,s2); s2 = fmaf(c.w,c.w,s2);
  s2 = fmaf(d.x,d.x,s2); s2 = fmaf(d.y,d.y,s2); s2 = fmaf(d.z,d.z,s2); s2 = fmaf(d.w,d.w,s2);
  // combine 4 quarters (adjacent lanes) -> full row norm on q==0 lanes
  float rn = s2 + __shfl_down(s2, 2) + __shfl_down(s2, 1)
                + __shfl_down(__shfl_down(s2, 2), 1);
  // simpler exact: lanes 4r..4r+3 hold quarters; do a 2-step butterfly
  float t1 = s2 + __shfl_xor(s2, 1);
  float t2 = t1 + __shfl_xor(t1, 2);
  if (q == 0) ws->e_norm[k] = t2;
  (void)rn;
  // block-reduce s2 -> sum_e2
  red[tid] = s2;
  __syncthreads();
  for (int off = 128; off > 0; off >>= 1) {
    if (tid < off) red[tid] += red[tid + off];
    __syncthreads();
  }
  if (tid == 0) atomicAdd(&ws->sum_e2, (double)red[0]);
  // column sums: threads 0..63, channel c = tid
  if (tid < CH) {
    float cs = 0.f;
    #pragma unroll 8
    for (int rr = 0; rr < 64; ++rr) cs += tile[rr][tid];
    atomicAdd(&ws->sum_e[tid], (double)cs);
  }
}

// ---- prep: per-channel sums of z + sum of z^2 ----------------------------
__global__ void vq_zsum(const float* __restrict__ z, Ws* __restrict__ ws) {
  // grid 256 blocks x 256 threads; block p handles plane (b = p>>6, c = p&63)
  const int p = blockIdx.x;
  const int tid = threadIdx.x;
  const float4* base = (const float4*)(z + (size_t)p * DHWC);
  float s = 0.f, s2 = 0.f;
  #pragma unroll 4
  for (int i = tid; i < DHWC / 4; i += 256) {
    float4 v = base[i];
    s += v.x + v.y + v.z + v.w;
    s2 = fmaf(v.x, v.x, s2); s2 = fmaf(v.y, v.y, s2);
    s2 = fmaf(v.z, v.z, s2); s2 = fmaf(v.w, v.w, s2);
  }
  __shared__ float sh[512];
  sh[tid] = s; sh[256 + tid] = s2;
  __syncthreads();
  for (int off = 128; off > 0; off >>= 1) {
    if (tid < off) { sh[tid] += sh[tid + off]; sh[256 + tid] += sh[256 + tid + off]; }
    __syncthreads();
  }
  if (tid == 0) {
    atomicAdd(&ws->sum_z[p & 63], (double)sh[0]);
    atomicAdd(&ws->sum_z2, (double)sh[256]);
  }
}

// ---- main: distances + argmin + gather + straight-through output ---------
__global__ __launch_bounds__(256, 4)
void vq_main(const float* __restrict__ z, const float* __restrict__ emb,
             float* __restrict__ out, Ws* __restrict__ ws) {
  const int tid  = threadIdx.x;
  const int lane = tid & 63;        // token within block
  const int w    = tid >> 6;        // wave id: handles codes [w*256, w*256+256)
  const int n    = blockIdx.x * 64 + lane;
  const int b    = n >> 14;         // n / 16384
  const int s    = n & 16383;
  const float* zb = z + (size_t)b * (CH * DHWC) + s;   // channel c at zb[c*DHWC]

  // token vector -> 64 VGPRs (coalesced: lanes differ in s)
  float zr[CH];
  #pragma unroll
  for (int c = 0; c < CH; ++c) zr[c] = zb[(size_t)c * DHWC];
  // PIN: opaque asm forces each value to live in a VGPR; prevents the
  // compiler from rematerializing these global loads inside the k-loop
  // (round-1 evidence: VGPR_Count=40 < 64 => zr was demoted, 225us at 54% VALUBusy)
  #pragma unroll
  for (int c = 0; c < CH; ++c) asm volatile("" : "+v"(zr[c]));

  float znorm = 0.f;
  #pragma unroll
  for (int c = 0; c < CH; ++c) znorm = fmaf(zr[c], zr[c], znorm);
  asm volatile("" : "+v"(znorm));

  // wave-uniform code range; readfirstlane so uniformity is provable -> s_load
  const int k0 = __builtin_amdgcn_readfirstlane(w * 256);
  const float* __restrict__ en = ws->e_norm;

  float best = 3.4e38f;
  int bestk = 0;
  for (int k = k0; k < k0 + 256; ++k) {
    const float4* __restrict__ e4 = (const float4*)(emb + (size_t)k * CH);
    float dot = 0.f;
    // exact serial chain c=0..63 (matches round-1's verified argmin behavior)
    #pragma unroll
    for (int i = 0; i < 16; ++i) {
      float4 v = e4[i];
      dot = fmaf(zr[4*i + 0], v.x, dot);
      dot = fmaf(zr[4*i + 1], v.y, dot);
      dot = fmaf(zr[4*i + 2], v.z, dot);
      dot = fmaf(zr[4*i + 3], v.w, dot);
    }
    // match reference rounding: t = fl(znorm + enorm); d = fl(t - 2*dot)
    float t = znorm + en[k];
    float d = fmaf(-2.f, dot, t);
    if (d < best) { best = d; bestk = k; }   // strict < keeps lowest k on ties
  }

  // combine the 4 per-wave results per token
  __shared__ float sd[256];
  __shared__ int   sk[256];
  sd[tid] = best; sk[tid] = bestk;
  __syncthreads();
  float fb = sd[lane];
  int   fk = sk[lane];
  #pragma unroll
  for (int j = 1; j < 4; ++j) {             // j ascending == k ascending
    float dj = sd[j * 64 + lane];
    int   kj = sk[j * 64 + lane];
    if (dj < fb) { fb = dj; fk = kj; }
  }
  if (w == 0) atomicAdd(&ws->counts[fk], 1);

  // epilogue: thread handles channels [w*16, w*16+16) of its token
  const float* __restrict__ eq = emb + (size_t)fk * CH;
  float lpart = 0.f;
  #pragma unroll
  for (int c2 = 0; c2 < 16; ++c2) {
    const int c = w * 16 + c2;
    float zc = zb[(size_t)c * DHWC];        // L1-hot reload (avoids dynamic VGPR indexing)
    float q  = eq[c];
    float dd = q - zc;                      // fl(z_q - z)
    out[(size_t)(b * CH + c) * DHWC + s] = zc + dd;   // straight-through, ref rounding
    lpart = fmaf(dd, dd, lpart);
  }

  __syncthreads();                          // sd free for reuse
  sd[tid] = lpart;
  __syncthreads();
  for (int off = 128; off > 0; off >>= 1) {
    if (tid < off) sd[tid] += sd[tid + off];
    __syncthreads();
  }
  if (tid == 0) atomicAdd(&ws->loss_sum, (double)sd[0]);
}

// ---- final: scalars ------------------------------------------------------
__global__ void vq_final(Ws* __restrict__ ws, float* __restrict__ out_scalars) {
  const int tid = threadIdx.x;              // 1 block x 1024 threads
  float p = (float)ws->counts[tid] * (1.0f / 65536.0f);
  float term = p * logf(p + 1e-10f);
  __shared__ float sh[1024];
  sh[tid] = term;
  __syncthreads();
  for (int off = 512; off > 0; off >>= 1) {
    if (tid < off) sh[tid] += sh[tid + off];
    __syncthreads();
  }
  if (tid == 0) {
    float perp = expf(-sh[0]);
    double m = ws->loss_sum / (double)OUT_ELEMS;
    float mf = (float)m;
    float loss = mf + 0.25f * mf;
    double sdot = 0.0;
    #pragma unroll
    for (int c = 0; c < CH; ++c) sdot += ws->sum_z[c] * ws->sum_e[c];
    double md = ws->sum_z2 / (double)NTOK + ws->sum_e2 / (double)KCODES
              - 2.0 * sdot / ((double)NTOK * (double)KCODES);
    out_scalars[0] = loss;
    out_scalars[1] = perp;
    out_scalars[2] = (float)md;
  }
}

extern "C" void kernel_launch(void* const* d_in, const int* in_sizes, int n_in,
                              void* d_out, int out_size, void* d_ws, size_t ws_size,
                              hipStream_t stream) {
  const float* z   = (const float*)d_in[0];
  const float* emb = (const float*)d_in[1];
  float* out = (float*)d_out;
  Ws* ws = (Ws*)d_ws;

  hipMemsetAsync(d_ws, 0, sizeof(Ws), stream);
  vq_eprep<<<16, 256, 0, stream>>>(emb, ws);
  vq_zsum <<<256, 256, 0, stream>>>(z, ws);
  vq_main <<<1024, 256, 0, stream>>>(z, emb, out, ws);
  vq_final<<<1, 1024, 0, stream>>>(ws, out + OUT_ELEMS);
}

// Round 3
// 193.372 us; speedup vs baseline: 1.8076x; 1.5010x over previous
//
#include <hip/hip_runtime.h>
#include <hip/hip_bf16.h>
#include <math.h>

// Problem shape: z [4,64,16,32,32] fp32, embedding [1024,64] fp32
// N = 65536 tokens, C = 64, K = 1024, DHW = 16384
#define CH     64
#define DHWC   16384
#define NTOK   65536
#define KCODES 1024
#define OUT_ELEMS 4194304
#define TB 128          // tokens per block
#define KT 128          // codes per k-tile
#define NKT 8           // k-tiles

struct Ws {
  double sum_z2;
  double sum_e2;
  double loss_sum;
  double pad;
  double sum_z[CH];
  double sum_e[CH];
  float  e_norm[KCODES];
  int    counts[KCODES];
  // transposed, tile-contiguous codebook: eT[tile][c][kk] = emb[tile*128+kk][c]
  float  eT[NKT * CH * KT];      // 256 KB
};

// ---- prep: e_norm + channel sums + sum_e2 + transposed tiled copy --------
// grid 16 x 256; block j handles codes [j*64, j*64+64)
__global__ void vq_eprep(const float* __restrict__ emb, Ws* __restrict__ ws) {
  __shared__ float tile[64][68];
  __shared__ float red[256];
  const int tid = threadIdx.x;
  const int r = tid >> 2;                 // code row within block tile (0..63)
  const int q = tid & 3;                  // quarter of the 64-channel row
  const int k = blockIdx.x * 64 + r;
  const float4* src = (const float4*)(emb + (size_t)k * CH + q * 16);
  float4 a = src[0], b = src[1], c = src[2], d = src[3];
  float4* dst = (float4*)(&tile[r][q * 16]);
  dst[0] = a; dst[1] = b; dst[2] = c; dst[3] = d;
  float s2 = 0.f;
  s2 = fmaf(a.x,a.x,s2); s2 = fmaf(a.y,a.y,s2); s2 = fmaf(a.z,a.z,s2); s2 = fmaf(a.w,a.w,s2);
  s2 = fmaf(b.x,b.x,s2); s2 = fmaf(b.y,b.y,s2); s2 = fmaf(b.z,b.z,s2); s2 = fmaf(b.w,b.w,s2);
  s2 = fmaf(c.x,c.x,s2); s2 = fmaf(c.y,c.y,s2); s2 = fmaf(c.z,c.z,s2); s2 = fmaf(c.w,c.w,s2);
  s2 = fmaf(d.x,d.x,s2); s2 = fmaf(d.y,d.y,s2); s2 = fmaf(d.z,d.z,s2); s2 = fmaf(d.w,d.w,s2);
  // verified-exact row norm (R2: absmax 0.0)
  float t1 = s2 + __shfl_xor(s2, 1);
  float t2 = t1 + __shfl_xor(t1, 2);
  if (q == 0) ws->e_norm[k] = t2;
  // transposed tiled copy straight from registers
  {
    const int tj = blockIdx.x >> 1;
    const int kk = ((blockIdx.x & 1) << 6) + r;
    float* dt = ws->eT + (size_t)tj * (CH * KT) + kk;   // + c*KT
    float vals[16] = {a.x,a.y,a.z,a.w, b.x,b.y,b.z,b.w,
                      c.x,c.y,c.z,c.w, d.x,d.y,d.z,d.w};
    #pragma unroll
    for (int u = 0; u < 16; ++u) dt[(size_t)(q * 16 + u) * KT] = vals[u];
  }
  red[tid] = s2;
  __syncthreads();
  for (int off = 128; off > 0; off >>= 1) {
    if (tid < off) red[tid] += red[tid + off];
    __syncthreads();
  }
  if (tid == 0) atomicAdd(&ws->sum_e2, (double)red[0]);
  if (tid < CH) {
    float cs = 0.f;
    #pragma unroll 8
    for (int rr = 0; rr < 64; ++rr) cs += tile[rr][tid];
    atomicAdd(&ws->sum_e[tid], (double)cs);
  }
}

// ---- prep: per-channel sums of z + sum of z^2 ----------------------------
__global__ void vq_zsum(const float* __restrict__ z, Ws* __restrict__ ws) {
  const int p = blockIdx.x;
  const int tid = threadIdx.x;
  const float4* base = (const float4*)(z + (size_t)p * DHWC);
  float s = 0.f, s2 = 0.f;
  #pragma unroll 4
  for (int i = tid; i < DHWC / 4; i += 256) {
    float4 v = base[i];
    s += v.x + v.y + v.z + v.w;
    s2 = fmaf(v.x, v.x, s2); s2 = fmaf(v.y, v.y, s2);
    s2 = fmaf(v.z, v.z, s2); s2 = fmaf(v.w, v.w, s2);
  }
  __shared__ float sh[512];
  sh[tid] = s; sh[256 + tid] = s2;
  __syncthreads();
  for (int off = 128; off > 0; off >>= 1) {
    if (tid < off) { sh[tid] += sh[tid + off]; sh[256 + tid] += sh[256 + tid + off]; }
    __syncthreads();
  }
  if (tid == 0) {
    atomicAdd(&ws->sum_z[p & 63], (double)sh[0]);
    atomicAdd(&ws->sum_z2, (double)sh[256]);
  }
}

// ---- main: register-blocked distance GEMM + argmin + output --------------
// grid 512 x 256; block handles 128 tokens (all in one b-plane: 16384/128=128)
__global__ __launch_bounds__(256, 2)
void vq_main(const float* __restrict__ z, const float* __restrict__ emb,
             float* __restrict__ out, Ws* __restrict__ ws) {
  __shared__ float zt[CH][TB];       // 32 KB, transposed z-tile [c][t]
  __shared__ float et[CH * KT];      // 32 KB, e-tile [c][kk]; reused post-loop
  __shared__ float znorm_s[TB];
  __shared__ int   win_k[TB];
  __shared__ float red[256];

  const int tid = threadIdx.x;
  const int b   = blockIdx.x >> 7;              // 128 blocks per batch-plane
  const int s0  = (blockIdx.x & 127) * TB;
  const float* zb = z + (size_t)b * (CH * DHWC) + s0;

  // ---- stage z-tile (coalesced float4; LDS rows are 512 B = bank-aligned)
  {
    const int t4 = (tid & 31) * 4;
    const int c0 = tid >> 5;                    // 0..7
    #pragma unroll
    for (int i = 0; i < 8; ++i) {
      const int c = c0 + 8 * i;
      float4 v = *(const float4*)(zb + (size_t)c * DHWC + t4);
      *(float4*)(&zt[c][t4]) = v;
    }
  }
  __syncthreads();

  // ---- z norms: exact serial fmaf chain c=0..63 (verified order, R1/R2)
  if (tid < TB) {
    float a = 0.f;
    #pragma unroll
    for (int c = 0; c < CH; ++c) a = fmaf(zt[c][tid], zt[c][tid], a);
    znorm_s[tid] = a;
  }
  __syncthreads();

  const int tx = tid & 15;                      // code group
  const int ty = tid >> 4;                      // token group
  float zn[8];
  #pragma unroll
  for (int u = 0; u < 8; ++u) zn[u] = znorm_s[ty * 8 + u];

  float bd[8];
  int   bk[8];
  #pragma unroll
  for (int u = 0; u < 8; ++u) { bd[u] = 3.4e38f; bk[u] = 0; }

  for (int j = 0; j < NKT; ++j) {
    // stage e-tile: flat coalesced copy from tile-contiguous eT
    {
      const float4* gsrc = (const float4*)(ws->eT + (size_t)j * (CH * KT));
      float4* ldst = (float4*)et;
      #pragma unroll
      for (int i = 0; i < 8; ++i) ldst[tid + i * 256] = gsrc[tid + i * 256];
    }
    __syncthreads();

    float enr[8];
    {
      const float* en = ws->e_norm + j * KT + tx * 8;
      *(float4*)&enr[0] = *(const float4*)(en);
      *(float4*)&enr[4] = *(const float4*)(en + 4);
    }

    float acc[8][8];
    #pragma unroll
    for (int u = 0; u < 8; ++u)
      #pragma unroll
      for (int v = 0; v < 8; ++v) acc[u][v] = 0.f;

    // dot accumulation: single fmaf chain over c ascending per (t,k) pair
    #pragma unroll 4
    for (int c = 0; c < CH; ++c) {
      float zv[8], ev[8];
      *(float4*)&zv[0] = *(const float4*)(&zt[c][ty * 8]);
      *(float4*)&zv[4] = *(const float4*)(&zt[c][ty * 8 + 4]);
      *(float4*)&ev[0] = *(const float4*)(&et[c * KT + tx * 8]);
      *(float4*)&ev[4] = *(const float4*)(&et[c * KT + tx * 8 + 4]);
      #pragma unroll
      for (int u = 0; u < 8; ++u)
        #pragma unroll
        for (int v = 0; v < 8; ++v)
          acc[u][v] = fmaf(zv[u], ev[v], acc[u][v]);
    }

    // distances + running argmin (k ascending, strict < => first-min)
    #pragma unroll
    for (int v = 0; v < 8; ++v) {
      const int k = j * KT + tx * 8 + v;
      #pragma unroll
      for (int u = 0; u < 8; ++u) {
        float t = zn[u] + enr[v];
        float d = fmaf(-2.f, acc[u][v], t);
        if (d < bd[u]) { bd[u] = d; bk[u] = k; }
      }
    }
    __syncthreads();   // et about to be overwritten (next tile or reduce)
  }

  // ---- cross-thread argmin combine (et reused; stride 17 kills conflicts)
  float* bd_s = et;                       // [TB][17] floats
  int*   bk_s = (int*)(et + TB * 17);     // [TB][17] ints
  #pragma unroll
  for (int u = 0; u < 8; ++u) {
    bd_s[(ty * 8 + u) * 17 + tx] = bd[u];
    bk_s[(ty * 8 + u) * 17 + tx] = bk[u];
  }
  __syncthreads();
  if (tid < TB) {
    float fb = bd_s[tid * 17];
    int   fk = bk_s[tid * 17];
    #pragma unroll
    for (int i = 1; i < 16; ++i) {
      float dj = bd_s[tid * 17 + i];
      int   kj = bk_s[tid * 17 + i];
      if (dj < fb || (dj == fb && kj < fk)) { fb = dj; fk = kj; }
    }
    win_k[tid] = fk;
    atomicAdd(&ws->counts[fk], 1);
  }
  __syncthreads();

  // ---- epilogue: gather + straight-through write + loss
  {
    const int g = tid >> 7;                     // channel half
    const int t = tid & 127;
    const int fk = win_k[t];
    const float* eq = emb + (size_t)fk * CH;
    float* ob = out + (size_t)b * (CH * DHWC) + s0 + t;
    float lpart = 0.f;
    #pragma unroll
    for (int jc = 0; jc < 32; ++jc) {
      const int c = g * 32 + jc;
      float zc = zt[c][t];
      float q  = eq[c];
      float dd = q - zc;                        // fl(z_q - z), ref rounding
      ob[(size_t)c * DHWC] = zc + dd;
      lpart = fmaf(dd, dd, lpart);
    }
    red[tid] = lpart;
  }
  __syncthreads();
  for (int off = 128; off > 0; off >>= 1) {
    if (tid < off) red[tid] += red[tid + off];
    __syncthreads();
  }
  if (tid == 0) atomicAdd(&ws->loss_sum, (double)red[0]);
}

// ---- final: scalars ------------------------------------------------------
__global__ void vq_final(Ws* __restrict__ ws, float* __restrict__ out_scalars) {
  const int tid = threadIdx.x;
  float p = (float)ws->counts[tid] * (1.0f / 65536.0f);
  float term = p * logf(p + 1e-10f);
  __shared__ float sh[1024];
  sh[tid] = term;
  __syncthreads();
  for (int off = 512; off > 0; off >>= 1) {
    if (tid < off) sh[tid] += sh[tid + off];
    __syncthreads();
  }
  if (tid == 0) {
    float perp = expf(-sh[0]);
    double m = ws->loss_sum / (double)OUT_ELEMS;
    float mf = (float)m;
    float loss = mf + 0.25f * mf;
    double sdot = 0.0;
    #pragma unroll
    for (int c = 0; c < CH; ++c) sdot += ws->sum_z[c] * ws->sum_e[c];
    double md = ws->sum_z2 / (double)NTOK + ws->sum_e2 / (double)KCODES
              - 2.0 * sdot / ((double)NTOK * (double)KCODES);
    out_scalars[0] = loss;
    out_scalars[1] = perp;
    out_scalars[2] = (float)md;
  }
}

extern "C" void kernel_launch(void* const* d_in, const int* in_sizes, int n_in,
                              void* d_out, int out_size, void* d_ws, size_t ws_size,
                              hipStream_t stream) {
  const float* z   = (const float*)d_in[0];
  const float* emb = (const float*)d_in[1];
  float* out = (float*)d_out;
  Ws* ws = (Ws*)d_ws;

  hipMemsetAsync(d_ws, 0, sizeof(Ws), stream);
  vq_eprep<<<16, 256, 0, stream>>>(emb, ws);
  vq_zsum <<<256, 256, 0, stream>>>(z, ws);
  vq_main <<<512, 256, 0, stream>>>(z, emb, out, ws);
  vq_final<<<1, 1024, 0, stream>>>(ws, out + OUT_ELEMS);
}

// Round 4
// 187.276 us; speedup vs baseline: 1.8664x; 1.0326x over previous
//
#include <hip/hip_runtime.h>
#include <hip/hip_bf16.h>
#include <math.h>
#include <stddef.h>

// Problem shape: z [4,64,16,32,32] fp32, embedding [1024,64] fp32
#define CH     64
#define DHWC   16384
#define NTOK   65536
#define KCODES 1024
#define OUT_ELEMS 4194304

typedef _Float16 f16;
typedef f16  f16x8  __attribute__((ext_vector_type(8)));
typedef float fltx4 __attribute__((ext_vector_type(4)));

struct Ws {
  // ---- zeroed header (memset range = offsetof(Ws, e_norm)) ----
  double sum_z2, sum_e2, loss_sum, pad;
  double sum_z[CH], sum_e[CH];
  int    counts[KCODES];
  // ---- filled by eprep ----
  float  e_norm[KCODES];
  float  accI[KCODES];            // -e_norm/2 (MFMA acc init)
  f16    e_hi[KCODES * CH];       // f16 codebook, [code][c] rows 128 B
  // ---- phase outputs ----
  unsigned short cand[NTOK * 4];  // top-4 candidates per token
  unsigned short win[NTOK];       // final argmin
};

// ---- eprep: e_norm (exact R1 chain) + channel sums + sum_e2 + f16 copy ---
// grid 16 x 256; block j handles codes [j*64, j*64+64)
__global__ void vq_eprep(const float* __restrict__ emb, Ws* __restrict__ ws) {
  __shared__ float tile[64][68];
  __shared__ float red[256];
  const int tid = threadIdx.x;
  const int r = tid >> 2;                 // code row within block (0..63)
  const int q = tid & 3;                  // quarter of the 64-channel row
  const int k = blockIdx.x * 64 + r;
  const float4* src = (const float4*)(emb + (size_t)k * CH + q * 16);
  float4 a = src[0], b = src[1], c = src[2], d = src[3];
  float4* dst = (float4*)(&tile[r][q * 16]);
  dst[0] = a; dst[1] = b; dst[2] = c; dst[3] = d;
  float s2 = 0.f;
  s2 = fmaf(a.x,a.x,s2); s2 = fmaf(a.y,a.y,s2); s2 = fmaf(a.z,a.z,s2); s2 = fmaf(a.w,a.w,s2);
  s2 = fmaf(b.x,b.x,s2); s2 = fmaf(b.y,b.y,s2); s2 = fmaf(b.z,b.z,s2); s2 = fmaf(b.w,b.w,s2);
  s2 = fmaf(c.x,c.x,s2); s2 = fmaf(c.y,c.y,s2); s2 = fmaf(c.z,c.z,s2); s2 = fmaf(c.w,c.w,s2);
  s2 = fmaf(d.x,d.x,s2); s2 = fmaf(d.y,d.y,s2); s2 = fmaf(d.z,d.z,s2); s2 = fmaf(d.w,d.w,s2);
  // verified-exact row norm (R1-R3: absmax 0.0)
  float t1 = s2 + __shfl_xor(s2, 1);
  float t2 = t1 + __shfl_xor(t1, 2);
  if (q == 0) { ws->e_norm[k] = t2; ws->accI[k] = -0.5f * t2; }
  // f16 codebook copy
  {
    float vals[16] = {a.x,a.y,a.z,a.w, b.x,b.y,b.z,b.w,
                      c.x,c.y,c.z,c.w, d.x,d.y,d.z,d.w};
    f16* dh = ws->e_hi + (size_t)k * CH + q * 16;
    #pragma unroll
    for (int u = 0; u < 16; ++u) dh[u] = (f16)vals[u];
  }
  red[tid] = s2;
  __syncthreads();
  for (int off = 128; off > 0; off >>= 1) {
    if (tid < off) red[tid] += red[tid + off];
    __syncthreads();
  }
  if (tid == 0) atomicAdd(&ws->sum_e2, (double)red[0]);
  if (tid < CH) {
    float cs = 0.f;
    #pragma unroll 8
    for (int rr = 0; rr < 64; ++rr) cs += tile[rr][tid];
    atomicAdd(&ws->sum_e[tid], (double)cs);
  }
}

// ---- phase 1: MFMA distance GEMM + per-class top-2 + top-4 narrowing -----
// grid 512 x 256; block = 128 tokens x all 1024 codes; wave = 32 tokens
__global__ __launch_bounds__(256, 4)
void vq_gemm(const float* __restrict__ z, Ws* __restrict__ ws) {
  __shared__ f16   zh[128 * 72];       // [token][c], row stride 72 halves
  __shared__ f16   zl[128 * 72];
  __shared__ float af[128 * 33];       // per-token 32 candidate accs
  __shared__ int   ak[128 * 33];

  const int tid = threadIdx.x;
  const int n0  = blockIdx.x * 128;
  const int b   = n0 >> 14;
  const int s0  = n0 & 16383;
  const float* zbase = z + (size_t)b * (CH * DHWC) + s0;

  // stage z -> f16 hi/lo, transposed to [token][c]
  {
    const int c = tid >> 2;            // 0..63
    const int q = tid & 3;             // 0..3
    const float4* src = (const float4*)(zbase + (size_t)c * DHWC) + q * 8;
    #pragma unroll
    for (int i = 0; i < 8; ++i) {
      float4 v = src[i];
      const int t0 = q * 32 + i * 4;
      float vv[4] = {v.x, v.y, v.z, v.w};
      #pragma unroll
      for (int u = 0; u < 4; ++u) {
        f16 h = (f16)vv[u];
        f16 l = (f16)(vv[u] - (float)h);
        zh[(t0 + u) * 72 + c] = h;
        zl[(t0 + u) * 72 + c] = l;
      }
    }
  }
  __syncthreads();

  const int lane = tid & 63;
  const int w    = tid >> 6;           // wave: tokens [w*32, w*32+32)
  const int nn   = lane & 15;          // MFMA tile column (code within 16)
  const int quad = lane >> 4;

  // A fragments: A[m=lane&15][k=quad*8+j]; token row = w*32 + mt*16 + nn
  f16x8 Ah[2][2], Al[2][2];
  #pragma unroll
  for (int mt = 0; mt < 2; ++mt) {
    const int row = w * 32 + mt * 16 + nn;
    #pragma unroll
    for (int ks = 0; ks < 2; ++ks) {
      const int off = row * 72 + ks * 32 + quad * 8;
      Ah[mt][ks] = *(const f16x8*)(&zh[off]);
      Al[mt][ks] = *(const f16x8*)(&zl[off]);
    }
  }

  // per-(token-slot, class) top-2 running max of acc (argmax acc == argmin d)
  float m1[8], m2[8]; int k1[8], k2[8];
  #pragma unroll
  for (int u = 0; u < 8; ++u) { m1[u] = -3.4e38f; m2[u] = -3.4e38f; k1[u] = 0; k2[u] = 0; }

  const f16*   __restrict__ eh = ws->e_hi;
  const float* __restrict__ aI = ws->accI;

  for (int ct = 0; ct < 64; ++ct) {
    const int krow = ct * 16 + nn;     // this lane's global code column
    // B fragments straight from global (L2-hot 128 KB codebook)
    f16x8 B0 = *(const f16x8*)(eh + (size_t)krow * CH + quad * 8);
    f16x8 B1 = *(const f16x8*)(eh + (size_t)krow * CH + 32 + quad * 8);
    const float ai = aI[krow];
    fltx4 acc0 = {ai, ai, ai, ai};
    fltx4 acc1 = {ai, ai, ai, ai};
    acc0 = __builtin_amdgcn_mfma_f32_16x16x32_f16(Ah[0][0], B0, acc0, 0, 0, 0);
    acc0 = __builtin_amdgcn_mfma_f32_16x16x32_f16(Al[0][0], B0, acc0, 0, 0, 0);
    acc0 = __builtin_amdgcn_mfma_f32_16x16x32_f16(Ah[0][1], B1, acc0, 0, 0, 0);
    acc0 = __builtin_amdgcn_mfma_f32_16x16x32_f16(Al[0][1], B1, acc0, 0, 0, 0);
    acc1 = __builtin_amdgcn_mfma_f32_16x16x32_f16(Ah[1][0], B0, acc1, 0, 0, 0);
    acc1 = __builtin_amdgcn_mfma_f32_16x16x32_f16(Al[1][0], B0, acc1, 0, 0, 0);
    acc1 = __builtin_amdgcn_mfma_f32_16x16x32_f16(Ah[1][1], B1, acc1, 0, 0, 0);
    acc1 = __builtin_amdgcn_mfma_f32_16x16x32_f16(Al[1][1], B1, acc1, 0, 0, 0);
    // top-2 insert; strict > keeps lowest k among equals (k scans ascending)
    #pragma unroll
    for (int r = 0; r < 4; ++r) {
      float a = acc0[r]; const int u = r;
      bool c1 = a > m1[u], c2 = a > m2[u];
      m2[u] = c1 ? m1[u] : (c2 ? a : m2[u]);
      k2[u] = c1 ? k1[u] : (c2 ? krow : k2[u]);
      m1[u] = c1 ? a : m1[u];
      k1[u] = c1 ? krow : k1[u];
    }
    #pragma unroll
    for (int r = 0; r < 4; ++r) {
      float a = acc1[r]; const int u = 4 + r;
      bool c1 = a > m1[u], c2 = a > m2[u];
      m2[u] = c1 ? m1[u] : (c2 ? a : m2[u]);
      k2[u] = c1 ? k1[u] : (c2 ? krow : k2[u]);
      m1[u] = c1 ? a : m1[u];
      k1[u] = c1 ? krow : k1[u];
    }
  }

  // dump per-class top-2: C/D row = quad*4 + reg (verified m89/m91)
  #pragma unroll
  for (int mt = 0; mt < 2; ++mt)
    #pragma unroll
    for (int r = 0; r < 4; ++r) {
      const int u = mt * 4 + r;
      const int tok = w * 32 + mt * 16 + quad * 4 + r;
      af[tok * 33 + nn * 2 + 0] = m1[u]; ak[tok * 33 + nn * 2 + 0] = k1[u];
      af[tok * 33 + nn * 2 + 1] = m2[u]; ak[tok * 33 + nn * 2 + 1] = k2[u];
    }
  __syncthreads();

  // narrow 32 -> top-4 by (acc desc, k asc); winner is in here w.h.p. >> 1-1e-6
  if (tid < 128) {
    float bv[4]; int bk4[4];
    #pragma unroll
    for (int u = 0; u < 4; ++u) { bv[u] = -3.4e38f; bk4[u] = 0x7fffffff; }
    for (int i = 0; i < 32; ++i) {
      float a = af[tid * 33 + i];
      int   k = ak[tid * 33 + i];
      #pragma unroll
      for (int j = 0; j < 4; ++j) {
        bool ins = (a > bv[j]) || (a == bv[j] && k < bk4[j]);
        float ta = bv[j]; int tk = bk4[j];
        bv[j]  = ins ? a : bv[j];   bk4[j] = ins ? k : bk4[j];
        a      = ins ? ta : a;      k      = ins ? tk : k;
      }
    }
    unsigned int* cd = (unsigned int*)(ws->cand + (size_t)(n0 + tid) * 4);
    cd[0] = (unsigned)bk4[0] | ((unsigned)bk4[1] << 16);
    cd[1] = (unsigned)bk4[2] | ((unsigned)bk4[3] << 16);
  }
}

// ---- phase 2: exact recheck of 4 candidates (verified R1 arithmetic) -----
// grid 256 x 256; thread = token
__global__ void vq_recheck(const float* __restrict__ z, const float* __restrict__ emb,
                           Ws* __restrict__ ws) {
  const int t = blockIdx.x * 256 + threadIdx.x;
  const int b = t >> 14;
  const int s = t & 16383;
  const float* zb = z + (size_t)b * (CH * DHWC) + s;
  // exact znorm: serial fmaf chain c=0..63 (verified R1)
  float znorm = 0.f;
  for (int c = 0; c < CH; ++c) {
    float v = zb[(size_t)c * DHWC];
    znorm = fmaf(v, v, znorm);
  }
  const unsigned int* cd = (const unsigned int*)(ws->cand + (size_t)t * 4);
  unsigned int c01 = cd[0], c23 = cd[1];
  int ks[4] = {(int)(c01 & 0xffff), (int)(c01 >> 16),
               (int)(c23 & 0xffff), (int)(c23 >> 16)};
  float fb = 3.4e38f; int fk = 0x7fffffff;
  #pragma unroll
  for (int j = 0; j < 4; ++j) {
    const int k = ks[j];
    const float* ek = emb + (size_t)k * CH;
    float dot = 0.f;
    for (int c = 0; c < CH; ++c)
      dot = fmaf(zb[(size_t)c * DHWC], ek[c], dot);
    float tt = znorm + ws->e_norm[k];
    float d  = fmaf(-2.f, dot, tt);               // exact reference rounding
    if (d < fb || (d == fb && k < fk)) { fb = d; fk = k; }
  }
  ws->win[t] = (unsigned short)fk;
  atomicAdd(&ws->counts[fk], 1);
}

// ---- phase 3: straight-through output + loss + z channel sums ------------
// grid 256 x 256; block = one (b,c) plane
__global__ void vq_writer(const float* __restrict__ z, const float* __restrict__ emb,
                          float* __restrict__ out, Ws* __restrict__ ws) {
  const int p = blockIdx.x;
  const int tid = threadIdx.x;
  const int b = p >> 6, c = p & 63;
  const float4* zp = (const float4*)(z + (size_t)p * DHWC);
  float4* op = (float4*)(out + (size_t)p * DHWC);
  const unsigned int* wn = (const unsigned int*)(ws->win + (size_t)b * DHWC);
  float s = 0.f, s2 = 0.f, lp = 0.f;
  for (int i = tid; i < DHWC / 4; i += 256) {
    float4 v = zp[i];
    unsigned int w0 = wn[2 * i], w1 = wn[2 * i + 1];
    float q0 = emb[(size_t)(w0 & 0xffff) * CH + c];
    float q1 = emb[(size_t)(w0 >> 16)   * CH + c];
    float q2 = emb[(size_t)(w1 & 0xffff) * CH + c];
    float q3 = emb[(size_t)(w1 >> 16)   * CH + c];
    float d0 = q0 - v.x, d1 = q1 - v.y, d2 = q2 - v.z, d3 = q3 - v.w;
    float4 o; o.x = v.x + d0; o.y = v.y + d1; o.z = v.z + d2; o.w = v.w + d3;
    op[i] = o;
    lp = fmaf(d0, d0, lp); lp = fmaf(d1, d1, lp);
    lp = fmaf(d2, d2, lp); lp = fmaf(d3, d3, lp);
    s += v.x + v.y + v.z + v.w;
    s2 = fmaf(v.x, v.x, s2); s2 = fmaf(v.y, v.y, s2);
    s2 = fmaf(v.z, v.z, s2); s2 = fmaf(v.w, v.w, s2);
  }
  __shared__ float sh[768];
  sh[tid] = s; sh[256 + tid] = s2; sh[512 + tid] = lp;
  __syncthreads();
  for (int off = 128; off > 0; off >>= 1) {
    if (tid < off) {
      sh[tid] += sh[tid + off];
      sh[256 + tid] += sh[256 + tid + off];
      sh[512 + tid] += sh[512 + tid + off];
    }
    __syncthreads();
  }
  if (tid == 0) {
    atomicAdd(&ws->sum_z[c], (double)sh[0]);
    atomicAdd(&ws->sum_z2, (double)sh[256]);
    atomicAdd(&ws->loss_sum, (double)sh[512]);
  }
}

// ---- final: scalars ------------------------------------------------------
__global__ void vq_final(Ws* __restrict__ ws, float* __restrict__ out_scalars) {
  const int tid = threadIdx.x;              // 1 block x 1024 threads
  float p = (float)ws->counts[tid] * (1.0f / 65536.0f);
  float term = p * logf(p + 1e-10f);
  __shared__ float sh[1024];
  sh[tid] = term;
  __syncthreads();
  for (int off = 512; off > 0; off >>= 1) {
    if (tid < off) sh[tid] += sh[tid + off];
    __syncthreads();
  }
  if (tid == 0) {
    float perp = expf(-sh[0]);
    double m = ws->loss_sum / (double)OUT_ELEMS;
    float mf = (float)m;
    float loss = mf + 0.25f * mf;
    double sdot = 0.0;
    #pragma unroll
    for (int c = 0; c < CH; ++c) sdot += ws->sum_z[c] * ws->sum_e[c];
    double md = ws->sum_z2 / (double)NTOK + ws->sum_e2 / (double)KCODES
              - 2.0 * sdot / ((double)NTOK * (double)KCODES);
    out_scalars[0] = loss;
    out_scalars[1] = perp;
    out_scalars[2] = (float)md;
  }
}

extern "C" void kernel_launch(void* const* d_in, const int* in_sizes, int n_in,
                              void* d_out, int out_size, void* d_ws, size_t ws_size,
                              hipStream_t stream) {
  const float* z   = (const float*)d_in[0];
  const float* emb = (const float*)d_in[1];
  float* out = (float*)d_out;
  Ws* ws = (Ws*)d_ws;

  hipMemsetAsync(d_ws, 0, offsetof(Ws, e_norm), stream);
  vq_eprep  <<<16,  256, 0, stream>>>(emb, ws);
  vq_gemm   <<<512, 256, 0, stream>>>(z, ws);
  vq_recheck<<<256, 256, 0, stream>>>(z, emb, ws);
  vq_writer <<<256, 256, 0, stream>>>(z, emb, out, ws);
  vq_final  <<<1, 1024, 0, stream>>>(ws, out + OUT_ELEMS);
}

// Round 5
// 166.577 us; speedup vs baseline: 2.0984x; 1.1243x over previous
//
#include <hip/hip_runtime.h>
#include <hip/hip_bf16.h>
#include <math.h>
#include <stddef.h>

// Problem shape: z [4,64,16,32,32] fp32, embedding [1024,64] fp32
#define CH     64
#define DHWC   16384
#define NTOK   65536
#define KCODES 1024
#define OUT_ELEMS 4194304

typedef _Float16 f16;
typedef f16  f16x8  __attribute__((ext_vector_type(8)));
typedef float fltx4 __attribute__((ext_vector_type(4)));

struct Ws {
  // ---- zeroed header (memset range = offsetof(Ws, e_norm)) ----
  double sum_z2, sum_e2, loss_sum, pad;
  double sum_z[CH], sum_e[CH];
  int    counts[KCODES];
  // ---- filled by eprep ----
  float  e_norm[KCODES];
  float  accI[KCODES];            // -e_norm/2 (fold into phase-1 ranking)
  f16    e_hi[KCODES * CH];       // f16 codebook, [code][c] rows 128 B
  // ---- phase output ----
  unsigned short win[NTOK];       // final argmin
};

// ---- eprep: e_norm (exact R1 chain) + channel sums + sum_e2 + f16 copy ---
__global__ void vq_eprep(const float* __restrict__ emb, Ws* __restrict__ ws) {
  __shared__ float tile[64][68];
  __shared__ float red[256];
  const int tid = threadIdx.x;
  const int r = tid >> 2;
  const int q = tid & 3;
  const int k = blockIdx.x * 64 + r;
  const float4* src = (const float4*)(emb + (size_t)k * CH + q * 16);
  float4 a = src[0], b = src[1], c = src[2], d = src[3];
  float4* dst = (float4*)(&tile[r][q * 16]);
  dst[0] = a; dst[1] = b; dst[2] = c; dst[3] = d;
  float s2 = 0.f;
  s2 = fmaf(a.x,a.x,s2); s2 = fmaf(a.y,a.y,s2); s2 = fmaf(a.z,a.z,s2); s2 = fmaf(a.w,a.w,s2);
  s2 = fmaf(b.x,b.x,s2); s2 = fmaf(b.y,b.y,s2); s2 = fmaf(b.z,b.z,s2); s2 = fmaf(b.w,b.w,s2);
  s2 = fmaf(c.x,c.x,s2); s2 = fmaf(c.y,c.y,s2); s2 = fmaf(c.z,c.z,s2); s2 = fmaf(c.w,c.w,s2);
  s2 = fmaf(d.x,d.x,s2); s2 = fmaf(d.y,d.y,s2); s2 = fmaf(d.z,d.z,s2); s2 = fmaf(d.w,d.w,s2);
  // verified-exact row norm (R1-R4: absmax 0.0)
  float t1 = s2 + __shfl_xor(s2, 1);
  float t2 = t1 + __shfl_xor(t1, 2);
  if (q == 0) { ws->e_norm[k] = t2; ws->accI[k] = -0.5f * t2; }
  {
    float vals[16] = {a.x,a.y,a.z,a.w, b.x,b.y,b.z,b.w,
                      c.x,c.y,c.z,c.w, d.x,d.y,d.z,d.w};
    f16* dh = ws->e_hi + (size_t)k * CH + q * 16;
    #pragma unroll
    for (int u = 0; u < 16; ++u) dh[u] = (f16)vals[u];
  }
  red[tid] = s2;
  __syncthreads();
  for (int off = 128; off > 0; off >>= 1) {
    if (tid < off) red[tid] += red[tid + off];
    __syncthreads();
  }
  if (tid == 0) atomicAdd(&ws->sum_e2, (double)red[0]);
  if (tid < CH) {
    float cs = 0.f;
    #pragma unroll 8
    for (int rr = 0; rr < 64; ++rr) cs += tile[rr][tid];
    atomicAdd(&ws->sum_e[tid], (double)cs);
  }
}

// ---- phase 1+2 fused: MFMA candidates + exact recheck --------------------
// grid 512 x 256; block = 128 tokens x all 1024 codes; wave = 32 tokens
__global__ __launch_bounds__(256, 4)
void vq_gemm(const float* __restrict__ z, const float* __restrict__ emb,
             Ws* __restrict__ ws) {
  // LDS: [0,18432) zh (f16 z-tile), later reused as cand2 (uint2[128*17]=17408)
  //      [18432,19456) csh  [19456,20480) rd  [20480,21504) rk
  __shared__ char smem[21504];
  f16*          zh    = (f16*)smem;
  uint2*        cand2 = (uint2*)smem;
  unsigned int* csh   = (unsigned int*)(smem + 18432);
  float*        rd    = (float*)(smem + 19456);
  int*          rk    = (int*)(smem + 20480);

  const int tid = threadIdx.x;
  const int n0  = blockIdx.x * 128;
  const int b   = n0 >> 14;
  const int s0  = n0 & 16383;
  const float* zbase = z + (size_t)b * (CH * DHWC) + s0;

  // stage z -> f16, transposed to [token][c] (stride 72 halves, 16B-aligned)
  {
    const int c = tid >> 2;            // 0..63
    const int q = tid & 3;             // token quarter
    const float4* src = (const float4*)(zbase + (size_t)c * DHWC) + q * 8;
    #pragma unroll
    for (int i = 0; i < 8; ++i) {
      float4 v = src[i];
      const int t0 = q * 32 + i * 4;
      zh[(t0 + 0) * 72 + c] = (f16)v.x;
      zh[(t0 + 1) * 72 + c] = (f16)v.y;
      zh[(t0 + 2) * 72 + c] = (f16)v.z;
      zh[(t0 + 3) * 72 + c] = (f16)v.w;
    }
  }
  __syncthreads();

  const int lane = tid & 63;
  const int w    = tid >> 6;           // wave: tokens [w*32, w*32+32)
  const int nn   = lane & 15;          // MFMA column (code class)
  const int quad = lane >> 4;

  // A fragments (R4-verified layout): A[m=lane&15][k=quad*8+j]
  f16x8 Ah[2][2];
  #pragma unroll
  for (int mt = 0; mt < 2; ++mt) {
    const int row = w * 32 + mt * 16 + nn;
    #pragma unroll
    for (int ks = 0; ks < 2; ++ks)
      Ah[mt][ks] = *(const f16x8*)(&zh[row * 72 + ks * 32 + quad * 8]);
  }

  // per-(token-slot, class) top-2 of (dot - enorm/2); argmax == argmin d
  float m1[8], m2[8]; int k1[8], k2[8];
  #pragma unroll
  for (int u = 0; u < 8; ++u) { m1[u] = -3.4e38f; m2[u] = -3.4e38f; k1[u] = 0; k2[u] = 0; }

  const f16*   __restrict__ eh = ws->e_hi;
  const float* __restrict__ aI = ws->accI;

  #pragma unroll 2
  for (int ct = 0; ct < 64; ++ct) {
    const int krow = ct * 16 + nn;
    f16x8 B0 = *(const f16x8*)(eh + (size_t)krow * CH + quad * 8);
    f16x8 B1 = *(const f16x8*)(eh + (size_t)krow * CH + 32 + quad * 8);
    const float ai = aI[krow];
    fltx4 zero4 = {0.f, 0.f, 0.f, 0.f};
    fltx4 acc0 = __builtin_amdgcn_mfma_f32_16x16x32_f16(Ah[0][0], B0, zero4, 0, 0, 0);
    acc0       = __builtin_amdgcn_mfma_f32_16x16x32_f16(Ah[0][1], B1, acc0,  0, 0, 0);
    fltx4 acc1 = __builtin_amdgcn_mfma_f32_16x16x32_f16(Ah[1][0], B0, zero4, 0, 0, 0);
    acc1       = __builtin_amdgcn_mfma_f32_16x16x32_f16(Ah[1][1], B1, acc1,  0, 0, 0);
    #pragma unroll
    for (int r = 0; r < 4; ++r) {
      float a = acc0[r] + ai; const int u = r;
      bool c1 = a > m1[u], c2 = a > m2[u];
      m2[u] = c1 ? m1[u] : (c2 ? a : m2[u]);
      k2[u] = c1 ? k1[u] : (c2 ? krow : k2[u]);
      m1[u] = c1 ? a : m1[u];
      k1[u] = c1 ? krow : k1[u];
    }
    #pragma unroll
    for (int r = 0; r < 4; ++r) {
      float a = acc1[r] + ai; const int u = 4 + r;
      bool c1 = a > m1[u], c2 = a > m2[u];
      m2[u] = c1 ? m1[u] : (c2 ? a : m2[u]);
      k2[u] = c1 ? k1[u] : (c2 ? krow : k2[u]);
      m1[u] = c1 ? a : m1[u];
      k1[u] = c1 ? krow : k1[u];
    }
  }

  // pre-merge neighbor classes (lane^1): 16 classes -> 8 pairs, top-2 each
  #pragma unroll
  for (int u = 0; u < 8; ++u) {
    float om1 = __shfl_xor(m1[u], 1), om2 = __shfl_xor(m2[u], 1);
    int   ok1 = __shfl_xor(k1[u], 1), ok2 = __shfl_xor(k2[u], 1);
    bool af = (m1[u] > om1) || (m1[u] == om1 && k1[u] < ok1);
    float w1 = af ? m1[u] : om1;  int wk1 = af ? k1[u] : ok1;
    float s2v = af ? m2[u] : om2; int sk2 = af ? k2[u] : ok2;   // winner's 2nd
    float l1 = af ? om1 : m1[u];  int lk1 = af ? ok1 : k1[u];   // loser's 1st
    bool sf = (s2v > l1) || (s2v == l1 && sk2 < lk1);
    m1[u] = w1; k1[u] = wk1;
    m2[u] = sf ? s2v : l1; k2[u] = sf ? sk2 : lk1;
  }

  __syncthreads();          // zh reads long done; safe to overwrite as cand2
  if (!(nn & 1)) {
    const int p = nn >> 1;  // class-pair 0..7
    #pragma unroll
    for (int mt = 0; mt < 2; ++mt)
      #pragma unroll
      for (int r = 0; r < 4; ++r) {
        const int u = mt * 4 + r;
        const int tok = w * 32 + mt * 16 + quad * 4 + r;  // C/D row (verified)
        uint2 e1; e1.x = __float_as_uint(m1[u]); e1.y = (unsigned)k1[u];
        uint2 e2; e2.x = __float_as_uint(m2[u]); e2.y = (unsigned)k2[u];
        cand2[tok * 17 + p * 2 + 0] = e1;
        cand2[tok * 17 + p * 2 + 1] = e2;
      }
  }
  __syncthreads();

  // narrow 16 -> top-4 per token by (value desc, k asc)
  if (tid < 128) {
    float bv[4]; int bk[4];
    #pragma unroll
    for (int u = 0; u < 4; ++u) { bv[u] = -3.4e38f; bk[u] = 0x7fffffff; }
    #pragma unroll 4
    for (int i = 0; i < 16; ++i) {
      uint2 e = cand2[tid * 17 + i];
      float a = __uint_as_float(e.x);
      int   k = (int)e.y;
      #pragma unroll
      for (int j = 0; j < 4; ++j) {
        bool ins = (a > bv[j]) || (a == bv[j] && k < bk[j]);
        float ta = bv[j]; int tk = bk[j];
        bv[j] = ins ? a : bv[j]; bk[j] = ins ? k : bk[j];
        a = ins ? ta : a; k = ins ? tk : k;
      }
    }
    csh[tid * 2 + 0] = (unsigned)bk[0] | ((unsigned)bk[1] << 16);
    csh[tid * 2 + 1] = (unsigned)bk[2] | ((unsigned)bk[3] << 16);
  }
  __syncthreads();

  // exact recheck (verified R1 arithmetic): half 0 -> cands 0,1; half 1 -> 2,3
  {
    const int t = tid & 127, half = tid >> 7;
    unsigned int cd = csh[t * 2 + half];
    const int ka = (int)(cd & 0xffff), kb = (int)(cd >> 16);
    const float* ea = emb + (size_t)ka * CH;
    const float* eb = emb + (size_t)kb * CH;
    const float* zt = zbase + t;
    float znorm = 0.f, da = 0.f, db = 0.f;
    for (int c = 0; c < CH; ++c) {
      float v = zt[(size_t)c * DHWC];
      znorm = fmaf(v, v, znorm);
      da = fmaf(v, ea[c], da);
      db = fmaf(v, eb[c], db);
    }
    float dda = fmaf(-2.f, da, znorm + ws->e_norm[ka]);
    float ddb = fmaf(-2.f, db, znorm + ws->e_norm[kb]);
    bool pa = (dda < ddb) || (dda == ddb && ka < kb);
    rd[tid] = pa ? dda : ddb;
    rk[tid] = pa ? ka : kb;
  }
  __syncthreads();
  if (tid < 128) {
    float d0 = rd[tid], d1 = rd[tid + 128];
    int   q0 = rk[tid], q1 = rk[tid + 128];
    bool p = (d0 < d1) || (d0 == d1 && q0 < q1);
    const int fk = p ? q0 : q1;
    ws->win[n0 + tid] = (unsigned short)fk;
    atomicAdd(&ws->counts[fk], 1);
  }
}

// ---- phase 3: straight-through output + loss + z channel sums ------------
// grid 256 x 256; block = one (b,c) plane
__global__ void vq_writer(const float* __restrict__ z, const float* __restrict__ emb,
                          float* __restrict__ out, Ws* __restrict__ ws) {
  const int p = blockIdx.x;
  const int tid = threadIdx.x;
  const int b = p >> 6, c = p & 63;
  const float4* zp = (const float4*)(z + (size_t)p * DHWC);
  float4* op = (float4*)(out + (size_t)p * DHWC);
  const unsigned int* wn = (const unsigned int*)(ws->win + (size_t)b * DHWC);
  float s = 0.f, s2 = 0.f, lp = 0.f;
  for (int i = tid; i < DHWC / 4; i += 256) {
    float4 v = zp[i];
    unsigned int w0 = wn[2 * i], w1 = wn[2 * i + 1];
    float q0 = emb[(size_t)(w0 & 0xffff) * CH + c];
    float q1 = emb[(size_t)(w0 >> 16)   * CH + c];
    float q2 = emb[(size_t)(w1 & 0xffff) * CH + c];
    float q3 = emb[(size_t)(w1 >> 16)   * CH + c];
    float d0 = q0 - v.x, d1 = q1 - v.y, d2 = q2 - v.z, d3 = q3 - v.w;
    float4 o; o.x = v.x + d0; o.y = v.y + d1; o.z = v.z + d2; o.w = v.w + d3;
    op[i] = o;
    lp = fmaf(d0, d0, lp); lp = fmaf(d1, d1, lp);
    lp = fmaf(d2, d2, lp); lp = fmaf(d3, d3, lp);
    s += v.x + v.y + v.z + v.w;
    s2 = fmaf(v.x, v.x, s2); s2 = fmaf(v.y, v.y, s2);
    s2 = fmaf(v.z, v.z, s2); s2 = fmaf(v.w, v.w, s2);
  }
  __shared__ float sh[768];
  sh[tid] = s; sh[256 + tid] = s2; sh[512 + tid] = lp;
  __syncthreads();
  for (int off = 128; off > 0; off >>= 1) {
    if (tid < off) {
      sh[tid] += sh[tid + off];
      sh[256 + tid] += sh[256 + tid + off];
      sh[512 + tid] += sh[512 + tid + off];
    }
    __syncthreads();
  }
  if (tid == 0) {
    atomicAdd(&ws->sum_z[c], (double)sh[0]);
    atomicAdd(&ws->sum_z2, (double)sh[256]);
    atomicAdd(&ws->loss_sum, (double)sh[512]);
  }
}

// ---- final: scalars ------------------------------------------------------
__global__ void vq_final(Ws* __restrict__ ws, float* __restrict__ out_scalars) {
  const int tid = threadIdx.x;
  float p = (float)ws->counts[tid] * (1.0f / 65536.0f);
  float term = p * logf(p + 1e-10f);
  __shared__ float sh[1024];
  sh[tid] = term;
  __syncthreads();
  for (int off = 512; off > 0; off >>= 1) {
    if (tid < off) sh[tid] += sh[tid + off];
    __syncthreads();
  }
  if (tid == 0) {
    float perp = expf(-sh[0]);
    double m = ws->loss_sum / (double)OUT_ELEMS;
    float mf = (float)m;
    float loss = mf + 0.25f * mf;
    double sdot = 0.0;
    #pragma unroll
    for (int c = 0; c < CH; ++c) sdot += ws->sum_z[c] * ws->sum_e[c];
    double md = ws->sum_z2 / (double)NTOK + ws->sum_e2 / (double)KCODES
              - 2.0 * sdot / ((double)NTOK * (double)KCODES);
    out_scalars[0] = loss;
    out_scalars[1] = perp;
    out_scalars[2] = (float)md;
  }
}

extern "C" void kernel_launch(void* const* d_in, const int* in_sizes, int n_in,
                              void* d_out, int out_size, void* d_ws, size_t ws_size,
                              hipStream_t stream) {
  const float* z   = (const float*)d_in[0];
  const float* emb = (const float*)d_in[1];
  float* out = (float*)d_out;
  Ws* ws = (Ws*)d_ws;

  hipMemsetAsync(d_ws, 0, offsetof(Ws, e_norm), stream);
  vq_eprep <<<16,  256, 0, stream>>>(emb, ws);
  vq_gemm  <<<512, 256, 0, stream>>>(z, emb, ws);
  vq_writer<<<256, 256, 0, stream>>>(z, emb, out, ws);
  vq_final <<<1, 1024, 0, stream>>>(ws, out + OUT_ELEMS);
}